// Round 1
// baseline (128.277 us; speedup 1.0000x reference)
//
#include <hip/hip_runtime.h>

#define BB 32
#define NN 4096
#define NQ 8
#define DD 64
#define DV 64
#define WAVES 8
#define TOK_PER_WAVE (NN / WAVES)   // 512 tokens per wave stripe
#define NGROUP (TOK_PER_WAVE / 8)   // 64 groups of 8 tokens

// DPP cross-lane add on the VALU pipe (no DS instruction, ~2-4 cyc latency).
template <int CTRL>
__device__ __forceinline__ float dpp_add(float x) {
    union { float f; int i; } in, out;
    in.f = x;
    out.i = __builtin_amdgcn_update_dpp(0, in.i, CTRL, 0xF, 0xF, true);
    return x + out.f;
}
// lane ^ 16 via ds_swizzle BitMode (within 32-lane halves: exact xor16)
__device__ __forceinline__ float swz16_add(float x) {
    union { float f; int i; } in, out;
    in.f = x;
    out.i = __builtin_amdgcn_ds_swizzle(in.i, 0x401F);
    return x + out.f;
}

// R11 HYPOTHESIS TEST: the 99us total is ~83us of per-iteration 256MiB
// workspace-poison fills (2x 41us fillBufferAligned @ 262144KB WRITE_SIZE in
// rocprof) + ~16us of kernels. This version uses NO workspace at all:
// one block per (b, v-half). Each block streams all 4096 tokens of its batch,
// computes the slot-softmax (token-local, needs all 8 slot scores -> full K
// rows) and the FULL renormalization denominator locally, but accumulates the
// numerator only for its 32-dim V slice. out = u/s written directly; no
// second kernel, no atomics, no d_ws.
//  - grid 64 = (b, h) pairs, XCD-swizzled so both halves of a batch share the
//    same XCD's L2 for the duplicated K read (K x2, V split disjoint).
//  - V slice = 128B-aligned half of each 256B token row -> one 128B line per
//    token, no fetch waste.
//  - (t,g) lane mapping, in-register softmax, DPP g-reduction, depth-3
//    prefetch all carried over verbatim from the verified R10 kernel.
//  - epilogue: per-wave DPP/swz16 reduce -> 16 partials (8 waves x 2 halves)
//    x 256 floats in LDS -> 256 threads sum + divide + store.
__global__ __launch_bounds__(512, 2) void slot_attn_fused(
    const float* __restrict__ keys, const float* __restrict__ values,
    const float* __restrict__ query, float* __restrict__ out)
{
    // XCD-aware decode: blocks (b,0),(b,1) get ids congruent mod 8 -> same XCD
    const int id  = blockIdx.x;
    const int xcd = id & 7;
    const int k   = id >> 3;              // 0..7
    const int b   = xcd + ((k >> 1) << 3);
    const int h   = k & 1;                // v-half

    const int tid   = threadIdx.x;
    const int wave  = tid >> 6;           // 0..7
    const int lane  = tid & 63;
    const int t_sub = lane >> 3;          // token within group (0..7)
    const int g     = lane & 7;           // dim octet (0..7)

    // Q octet g for all 8 slots, pre-scaled by 1/sqrt(64)
    float4 q0[8], q1[8];
    const float* qb = query + (size_t)b * NQ * DD + 8 * g;
#pragma unroll
    for (int m = 0; m < 8; ++m) {
        float4 a = *(const float4*)(qb + m * DD);
        float4 c = *(const float4*)(qb + m * DD + 4);
        a.x *= 0.125f; a.y *= 0.125f; a.z *= 0.125f; a.w *= 0.125f;
        c.x *= 0.125f; c.y *= 0.125f; c.z *= 0.125f; c.w *= 0.125f;
        q0[m] = a; q1[m] = c;
    }

    const int tok0 = wave * TOK_PER_WAVE;
    const float* Kbase = keys   + ((size_t)b * NN + tok0) * DD + 8 * g;
    // V: 32-float slice [h*32, h*32+32); lane g owns floats [4g, 4g+4)
    const float* Vbase = values + ((size_t)b * NN + tok0) * DV + h * 32 + 4 * g;

    float u[8][4];
#pragma unroll
    for (int m = 0; m < 8; ++m)
#pragma unroll
        for (int j = 0; j < 4; ++j) u[m][j] = 0.f;
    float s_acc[8];
#pragma unroll
    for (int m = 0; m < 8; ++m) s_acc[m] = 0.f;

    // quad-buffered register batches (depth-3 prefetch)
    float4 kb0[4], kb1[4], vb[4];
#pragma unroll
    for (int p = 0; p < 3; ++p) {
        const float4* kp = (const float4*)(Kbase + (size_t)(8 * p + t_sub) * DD);
        kb0[p] = kp[0]; kb1[p] = kp[1];
        vb[p]  = *(const float4*)(Vbase + (size_t)(8 * p + t_sub) * DV);
    }

#pragma unroll 4
    for (int i = 0; i < NGROUP; ++i) {
        const int cur = i & 3;
        if (i + 3 < NGROUP) {
            const int nxt = (i + 3) & 3;
            const float4* kp = (const float4*)(Kbase + (size_t)(8 * (i + 3) + t_sub) * DD);
            kb0[nxt] = kp[0]; kb1[nxt] = kp[1];
            vb[nxt]  = *(const float4*)(Vbase + (size_t)(8 * (i + 3) + t_sub) * DV);
        }

        const float4 kc0 = kb0[cur], kc1 = kb1[cur];
        float s[8];
#pragma unroll
        for (int m = 0; m < 8; ++m) {
            s[m] = kc0.x * q0[m].x + kc0.y * q0[m].y + kc0.z * q0[m].z + kc0.w * q0[m].w
                 + kc1.x * q1[m].x + kc1.y * q1[m].y + kc1.z * q1[m].z + kc1.w * q1[m].w;
        }
        // g-reduction entirely on VALU via DPP (no DS ops)
#pragma unroll
        for (int m = 0; m < 8; ++m) {
            s[m] = dpp_add<0xB1>(s[m]);   // + lane^1 (quad_perm 1,0,3,2)
            s[m] = dpp_add<0x4E>(s[m]);   // + lane^2 (quad_perm 2,3,0,1)
            s[m] = dpp_add<0x141>(s[m]);  // + lane^7 == xor4 (quad-uniform)
        }
        // softmax over m, in-register (no max-sub: scores ~N(0,1), fp32-safe)
        float e[8], sum = 0.f;
#pragma unroll
        for (int m = 0; m < 8; ++m) { e[m] = __expf(s[m]); sum += e[m]; }
        const float r = __builtin_amdgcn_rcpf(sum);
        const float4 vc = vb[cur];
#pragma unroll
        for (int m = 0; m < 8; ++m) {
            const float a = e[m] * r + 1e-8f;
            s_acc[m] += a;
            u[m][0] += a * vc.x; u[m][1] += a * vc.y;
            u[m][2] += a * vc.z; u[m][3] += a * vc.w;
        }
    }

    // epilogue: reduce t_sub bits 0,1 (lane^8 via row_ror:8 — exact;
    // lane^16 via ds_swizzle); bit 2 (lane^32) via 16-partial LDS reduce.
#pragma unroll
    for (int m = 0; m < 8; ++m) {
#pragma unroll
        for (int j = 0; j < 4; ++j) {
            u[m][j] = dpp_add<0x128>(u[m][j]);
            u[m][j] = swz16_add(u[m][j]);
        }
        s_acc[m] = dpp_add<0x128>(s_acc[m]);
        s_acc[m] = swz16_add(s_acc[m]);
    }

    __shared__ float lds[16 * 256];   // 16 partial rows x (8 slots x 32 v)
    __shared__ float lds_s[16 * 8];
    const int half = lane >> 5;
    if ((lane & 24) == 0) {  // lanes 0-7 and 32-39 hold the half-sums
        float* dst = lds + (wave * 2 + half) * 256 + 4 * g;
#pragma unroll
        for (int m = 0; m < 8; ++m)
            *(float4*)(dst + m * 32) = make_float4(u[m][0], u[m][1], u[m][2], u[m][3]);
        if (g == 0) {
#pragma unroll
            for (int m = 0; m < 8; ++m) lds_s[(wave * 2 + half) * 8 + m] = s_acc[m];
        }
    }
    __syncthreads();

    if (tid < 256) {
        float usum = 0.f;
#pragma unroll
        for (int p = 0; p < 16; ++p) usum += lds[p * 256 + tid];
        const int m = tid >> 5;
        float ssum = 0.f;
#pragma unroll
        for (int p = 0; p < 16; ++p) ssum += lds_s[p * 8 + m];
        out[(size_t)b * (NQ * DV) + m * DV + h * 32 + (tid & 31)] = usum / ssum;
    }
}

extern "C" void kernel_launch(void* const* d_in, const int* in_sizes, int n_in,
                              void* d_out, int out_size, void* d_ws, size_t ws_size,
                              hipStream_t stream) {
    const float* keys   = (const float*)d_in[0];
    const float* values = (const float*)d_in[1];
    const float* query  = (const float*)d_in[2];
    (void)d_ws; (void)ws_size;  // deliberately unused: testing ws-poison hypothesis

    slot_attn_fused<<<dim3(64), 512, 0, stream>>>(keys, values, query, (float*)d_out);
}

// Round 2
// 114.607 us; speedup vs baseline: 1.1193x; 1.1193x over previous
//
#include <hip/hip_runtime.h>

#define BB 32
#define NN 4096
#define NQ 8
#define DD 64
#define DV 64
#define CHUNKS 16
#define TOK_PER_BLOCK (NN / CHUNKS)      // 256
#define TOK_PER_WAVE (TOK_PER_BLOCK / 4) // 64
#define NGROUP (TOK_PER_WAVE / 8)        // 8 groups of 8 tokens

// DPP cross-lane add on the VALU pipe (no DS instruction, ~2-4 cyc latency).
template <int CTRL>
__device__ __forceinline__ float dpp_add(float x) {
    union { float f; int i; } in, out;
    in.f = x;
    out.i = __builtin_amdgcn_update_dpp(0, in.i, CTRL, 0xF, 0xF, true);
    return x + out.f;
}
// lane ^ 16 via ds_swizzle BitMode (within 32-lane halves: exact xor16)
__device__ __forceinline__ float swz16_add(float x) {
    union { float f; int i; } in, out;
    in.f = x;
    out.i = __builtin_amdgcn_ds_swizzle(in.i, 0x401F);
    return x + out.f;
}

// R12: time model = 83us unconditional ws-poison fills + kernels (R1 showed
// ws-free does NOT remove the fills; dur 128 = 83 + ~45 in-graph kernel).
// So: back to the verified two-kernel structure, and push the partial kernel
// from 4.6 TB/s toward the 6.3 TB/s floor. R0's partial was 220 VGPR
// (u[8][8] + q resident) -> 2 waves/SIMD. R1 proved the same inner loop with
// a half-V split (u[8][4]) fits 112 VGPR -> here: one block per
// (chunk, v-half, b), launch_bounds(256,4) -> 4 blocks/CU, 16 waves/CU (2x).
// K is read by both halves of a pair: blockIdx.x = h*16+c puts the pair's
// linear ids 16 apart (== mod 8) -> same XCD -> 2nd K read hits that XCD's
// L2; HBM still sees K once. V halves are disjoint 128B slices (no waste).
// Denominator is V-independent: both halves compute it, only h==0 writes PS.
// DO NOT re-fuse the final reduce into this kernel (R8/R9: fused epilogue
// forced allocator into spilling config, 16->85us).
__global__ __launch_bounds__(256, 4) void slot_attn_partial(
    const float* __restrict__ keys, const float* __restrict__ values,
    const float* __restrict__ query, float* __restrict__ PU, float* __restrict__ PS)
{
    const int b     = blockIdx.y;
    const int chnk  = blockIdx.x & 15;   // chunk 0..15
    const int hb    = blockIdx.x >> 4;   // v-half 0/1
    const int tid   = threadIdx.x;
    const int wave  = tid >> 6;
    const int lane  = tid & 63;
    const int t_sub = lane >> 3;  // token within group (0..7)
    const int g     = lane & 7;   // dim octet (0..7)

    // Q octet g for all 8 slots, pre-scaled by 1/sqrt(64)
    float4 q0[8], q1[8];
    const float* qb = query + (size_t)b * NQ * DD + 8 * g;
#pragma unroll
    for (int m = 0; m < 8; ++m) {
        float4 a = *(const float4*)(qb + m * DD);
        float4 c = *(const float4*)(qb + m * DD + 4);
        a.x *= 0.125f; a.y *= 0.125f; a.z *= 0.125f; a.w *= 0.125f;
        c.x *= 0.125f; c.y *= 0.125f; c.z *= 0.125f; c.w *= 0.125f;
        q0[m] = a; q1[m] = c;
    }

    const int tok0 = chnk * TOK_PER_BLOCK + wave * TOK_PER_WAVE;
    const float* Kbase = keys   + ((size_t)b * NN + tok0) * DD + 8 * g;
    // V: this block covers floats [hb*32, hb*32+32) of each row; lane g owns 4
    const float* Vbase = values + ((size_t)b * NN + tok0) * DV + hb * 32 + 4 * g;

    float u[8][4];
#pragma unroll
    for (int m = 0; m < 8; ++m)
#pragma unroll
        for (int j = 0; j < 4; ++j) u[m][j] = 0.f;
    float s_acc[8];
#pragma unroll
    for (int m = 0; m < 8; ++m) s_acc[m] = 0.f;

    // quad-buffered register batches (depth-3 prefetch)
    float4 kb0[4], kb1[4], vb[4];
#pragma unroll
    for (int p = 0; p < 3; ++p) {
        const float4* kp = (const float4*)(Kbase + (size_t)(8 * p + t_sub) * DD);
        kb0[p] = kp[0]; kb1[p] = kp[1];
        vb[p]  = *(const float4*)(Vbase + (size_t)(8 * p + t_sub) * DV);
    }

#pragma unroll
    for (int i = 0; i < NGROUP; ++i) {
        const int cur = i & 3;
        if (i + 3 < NGROUP) {
            const int nxt = (i + 3) & 3;
            const float4* kp = (const float4*)(Kbase + (size_t)(8 * (i + 3) + t_sub) * DD);
            kb0[nxt] = kp[0]; kb1[nxt] = kp[1];
            vb[nxt]  = *(const float4*)(Vbase + (size_t)(8 * (i + 3) + t_sub) * DV);
        }

        const float4 kc0 = kb0[cur], kc1 = kb1[cur];
        float s[8];
#pragma unroll
        for (int m = 0; m < 8; ++m) {
            s[m] = kc0.x * q0[m].x + kc0.y * q0[m].y + kc0.z * q0[m].z + kc0.w * q0[m].w
                 + kc1.x * q1[m].x + kc1.y * q1[m].y + kc1.z * q1[m].z + kc1.w * q1[m].w;
        }
        // g-reduction entirely on VALU via DPP (no DS ops)
#pragma unroll
        for (int m = 0; m < 8; ++m) {
            s[m] = dpp_add<0xB1>(s[m]);   // + lane^1 (quad_perm 1,0,3,2)
            s[m] = dpp_add<0x4E>(s[m]);   // + lane^2 (quad_perm 2,3,0,1)
            s[m] = dpp_add<0x141>(s[m]);  // + lane^7 == xor4 (quad-uniform)
        }
        // softmax over m, in-register (no max-sub: scores ~N(0,1), fp32-safe)
        float e[8], sum = 0.f;
#pragma unroll
        for (int m = 0; m < 8; ++m) { e[m] = __expf(s[m]); sum += e[m]; }
        const float r = __builtin_amdgcn_rcpf(sum);
        const float4 vc = vb[cur];
#pragma unroll
        for (int m = 0; m < 8; ++m) {
            const float a = e[m] * r + 1e-8f;
            s_acc[m] += a;
            u[m][0] += a * vc.x; u[m][1] += a * vc.y;
            u[m][2] += a * vc.z; u[m][3] += a * vc.w;
        }
    }

    // epilogue: reduce t_sub bits 0,1 (lane^8 via row_ror:8 — exact;
    // lane^16 via ds_swizzle); bit 2 (lane^32) via 8-partial LDS reduce.
#pragma unroll
    for (int m = 0; m < 8; ++m) {
#pragma unroll
        for (int j = 0; j < 4; ++j) {
            u[m][j] = dpp_add<0x128>(u[m][j]);
            u[m][j] = swz16_add(u[m][j]);
        }
        s_acc[m] = dpp_add<0x128>(s_acc[m]);
        s_acc[m] = swz16_add(s_acc[m]);
    }

    __shared__ float lds[8 * 256];   // 8 partial rows x (8 slots x 32 v)
    __shared__ float lds_s[8 * 8];
    const int half = lane >> 5;
    if ((lane & 24) == 0) {  // lanes 0-7 and 32-39 hold the half-sums
        float* dst = lds + (wave * 2 + half) * 256 + 4 * g;
#pragma unroll
        for (int m = 0; m < 8; ++m)
            *(float4*)(dst + m * 32) = make_float4(u[m][0], u[m][1], u[m][2], u[m][3]);
        if (g == 0) {
#pragma unroll
            for (int m = 0; m < 8; ++m) lds_s[(wave * 2 + half) * 8 + m] = s_acc[m];
        }
    }
    __syncthreads();

    // PU layout: [b][c][hb][m][32]
    float* pu = PU + (((size_t)b * CHUNKS + chnk) * 2 + hb) * 256;
    {
        float sum = 0.f;
#pragma unroll
        for (int k = 0; k < 8; ++k) sum += lds[k * 256 + tid];
        pu[tid] = sum;
    }
    if (hb == 0 && tid < 8) {
        float ssum = 0.f;
#pragma unroll
        for (int k = 0; k < 8; ++k) ssum += lds_s[k * 8 + tid];
        PS[((size_t)b * CHUNKS + chnk) * 8 + tid] = ssum;
    }
}

// Stage 2: out[b][m][v] = (sum_c PU[b][c][v>>5][m*32+(v&31)]) / (sum_c PS[b][c][m])
__global__ __launch_bounds__(512) void slot_attn_reduce(
    const float* __restrict__ PU, const float* __restrict__ PS,
    float* __restrict__ out)
{
    const int b = blockIdx.x;
    const int i = threadIdx.x;  // 0..511

    __shared__ float ssum[NQ];
    if (i < NQ) {
        float s = 0.f;
        const float* ps = PS + (size_t)b * CHUNKS * 8 + i;
#pragma unroll
        for (int c = 0; c < CHUNKS; ++c) s += ps[c * 8];
        ssum[i] = s;
    }
    __syncthreads();

    const int m  = i >> 6;
    const int v  = i & 63;
    const int h  = v >> 5;
    const int vp = v & 31;
    float usum = 0.f;
    const float* pu = PU + (size_t)b * (CHUNKS * 2 * 256) + h * 256 + m * 32 + vp;
#pragma unroll
    for (int c = 0; c < CHUNKS; ++c) usum += pu[c * 512];
    out[(size_t)b * 512 + i] = usum / ssum[m];
}

extern "C" void kernel_launch(void* const* d_in, const int* in_sizes, int n_in,
                              void* d_out, int out_size, void* d_ws, size_t ws_size,
                              hipStream_t stream) {
    const float* keys   = (const float*)d_in[0];
    const float* values = (const float*)d_in[1];
    const float* query  = (const float*)d_in[2];
    float* out = (float*)d_out;

    float* PU = (float*)d_ws;                           // BB*CHUNKS*2*256 floats
    float* PS = PU + (size_t)BB * CHUNKS * 2 * 256;     // BB*CHUNKS*8 floats

    // blockIdx.x = hb*16 + c: pair (c,0)/(c,1) ids differ by 16 == 0 mod 8
    // -> same XCD -> shared-K L2 locality.
    slot_attn_partial<<<dim3(CHUNKS * 2, BB), 256, 0, stream>>>(keys, values, query, PU, PS);
    slot_attn_reduce<<<dim3(BB), 512, 0, stream>>>(PU, PS, out);
}